// Round 6
// baseline (113.021 us; speedup 1.0000x reference)
//
#include <hip/hip_runtime.h>
#include <math.h>

// NetVLAD: B=8, N=2048, D=128, K=64, fp32 in/out.
#define BB 8
#define NN 2048
#define DD 128
#define KK 64
#define PP 128           // blocks per batch for K1 (1024 blocks = 4/CU)
#define NPB (NN / PP)    // 16 descriptors per block, one pass

// ---------------------------------------------------------------------------
// K1 v6: v5 structure with the SPILLS removed (round-5 counters: VGPR=64
// allocation vs ~110 live floats -> +92 MB scratch writes, +23 MB reloads).
//   - e0/e1 register arrays (32 VGPRs) -> eL[16][64] in LDS (4 KB).
//   - cA/cB released after Phase B; epilogue re-loads centroid fragments
//     from cent (L2-hot) for the -sumA*c fold.
//   Peak live state ~50-60 floats -> fits the 64-VGPR allocation, no scratch.
// Structure otherwise identical to v5: 2 barriers, fold in epilogue,
// part_sA eliminated.
// ---------------------------------------------------------------------------
__global__ __launch_bounds__(256, 4) void netvlad_k1(
    const float* __restrict__ x, const float* __restrict__ cent,
    float* __restrict__ part_acc)
{
    const int b    = blockIdx.x >> 7;    // / PP
    const int p    = blockIdx.x & 127;   // % PP
    const int t    = threadIdx.x;
    const int kq   = t >> 3;             // 0..31: owns k = {2kq, 2kq+1}
    const int pr   = t & 7;              // 0..7: owns d-range [pr*16, +16)
    const int dbase = pr * 16;
    const int wave = t >> 6;

    __shared__ __align__(16) float xs[NPB][DD];  // 8 KB: normalized descriptors
    __shared__ __align__(8)  float eL[NPB][KK];  // 4 KB: exp values
    __shared__ __align__(16) float sL[NPB][4];   // per-wave exp-sum partials

    // Rotated chunk offsets: slot jj -> chunk ((jj+pr)&3) of the 16-float
    // range (2-way bank alias max, free on gfx950).
    int off[4];
    #pragma unroll
    for (int jj = 0; jj < 4; ++jj) off[jj] = dbase + (((jj + pr) & 3) << 2);

    // ---- issue x loads first: row i0 = t>>4, floats [tl*4,+4) & [64+tl*4,+4)
    const int i0 = t >> 4, tl = t & 15;
    const float* xr = x + ((size_t)b * NN + (size_t)p * NPB + i0) * DD;
    float4 v0 = *(const float4*)(xr + tl * 4);
    float4 v1 = *(const float4*)(xr + 64 + tl * 4);

    // ---- centroid fragments + ||c_k||^2 (independent chain, overlaps loads)
    float4 cA[4], cB[4];
    float cn2a = 0.f, cn2b = 0.f;
    #pragma unroll
    for (int jj = 0; jj < 4; ++jj) {
        cA[jj] = *(const float4*)(cent + (2 * kq) * DD + off[jj]);
        cB[jj] = *(const float4*)(cent + (2 * kq + 1) * DD + off[jj]);
        cn2a += cA[jj].x*cA[jj].x + cA[jj].y*cA[jj].y + cA[jj].z*cA[jj].z + cA[jj].w*cA[jj].w;
        cn2b += cB[jj].x*cB[jj].x + cB[jj].y*cB[jj].y + cB[jj].z*cB[jj].z + cB[jj].w*cB[jj].w;
    }
    #pragma unroll
    for (int m = 1; m < 8; m <<= 1) {
        cn2a += __shfl_xor(cn2a, m);
        cn2b += __shfl_xor(cn2b, m);
    }

    // ---- normalize row i0 in registers, write xs once
    {
        float ss = v0.x*v0.x + v0.y*v0.y + v0.z*v0.z + v0.w*v0.w
                 + v1.x*v1.x + v1.y*v1.y + v1.z*v1.z + v1.w*v1.w;
        #pragma unroll
        for (int m = 1; m < 16; m <<= 1) ss += __shfl_xor(ss, m);
        const float rn = 1.0f / fmaxf(sqrtf(ss), 1e-12f);
        v0.x *= rn; v0.y *= rn; v0.z *= rn; v0.w *= rn;
        v1.x *= rn; v1.y *= rn; v1.z *= rn; v1.w *= rn;
        *(float4*)(&xs[i0][tl * 4])      = v0;
        *(float4*)(&xs[i0][64 + tl * 4]) = v1;
    }
    __syncthreads();   // bar 1: normalized tile visible

    // ---- Phase B: dots + exp.  assign ∝ exp(||c||^2 - 2 xn·c).
    // e values go straight to LDS (no register arrays -> no spills).
    #pragma unroll
    for (int i = 0; i < NPB; ++i) {
        float S0 = 0.f, S1 = 0.f;
        #pragma unroll
        for (int jj = 0; jj < 4; ++jj) {
            float4 v = *(const float4*)(&xs[i][off[jj]]);
            S0 += v.x*cA[jj].x + v.y*cA[jj].y + v.z*cA[jj].z + v.w*cA[jj].w;
            S1 += v.x*cB[jj].x + v.y*cB[jj].y + v.z*cB[jj].z + v.w*cB[jj].w;
        }
        #pragma unroll
        for (int m = 1; m < 8; m <<= 1) {   // reduce across the 8 d-parts
            S0 += __shfl_xor(S0, m);
            S1 += __shfl_xor(S1, m);
        }
        const float e0 = __expf(cn2a - 2.f * S0);
        const float e1 = __expf(cn2b - 2.f * S1);
        if (pr == 0) *(float2*)(&eL[i][2 * kq]) = make_float2(e0, e1);
        // per-wave softmax partial: sum this wave's 16 k's
        float es = e0 + e1;
        #pragma unroll
        for (int m = 8; m < 64; m <<= 1) es += __shfl_xor(es, m);
        if ((t & 63) == 0) sL[i][wave] = es;
    }
    __syncthreads();   // bar 2: eL + sL complete

    // ---- Phase C: accumulate assign * xn (cA/cB dead here — low pressure)
    float4 acc0[4], acc1[4];
    #pragma unroll
    for (int jj = 0; jj < 4; ++jj) {
        acc0[jj] = make_float4(0.f, 0.f, 0.f, 0.f);
        acc1[jj] = make_float4(0.f, 0.f, 0.f, 0.f);
    }
    float sA0 = 0.f, sA1 = 0.f;
    #pragma unroll
    for (int i = 0; i < NPB; ++i) {
        const float4 s4 = *(const float4*)(&sL[i][0]);       // broadcast
        const float rs = 1.0f / (s4.x + s4.y + s4.z + s4.w);
        const float2 e2 = *(const float2*)(&eL[i][2 * kq]);  // 8-lane broadcast
        const float a0 = e2.x * rs, a1 = e2.y * rs;
        sA0 += a0; sA1 += a1;
        #pragma unroll
        for (int jj = 0; jj < 4; ++jj) {
            float4 v = *(const float4*)(&xs[i][off[jj]]);
            acc0[jj].x += a0*v.x; acc0[jj].y += a0*v.y; acc0[jj].z += a0*v.z; acc0[jj].w += a0*v.w;
            acc1[jj].x += a1*v.x; acc1[jj].y += a1*v.y; acc1[jj].z += a1*v.z; acc1[jj].w += a1*v.w;
        }
    }

    // ---- epilogue: re-load centroid frags (L2-hot), fold -sumA*c, write
    const size_t base = (size_t)(b * PP + p) * KK * DD;
    #pragma unroll
    for (int jj = 0; jj < 4; ++jj) {
        const float4 c0 = *(const float4*)(cent + (2 * kq) * DD + off[jj]);
        const float4 c1 = *(const float4*)(cent + (2 * kq + 1) * DD + off[jj]);
        acc0[jj].x -= sA0 * c0.x; acc0[jj].y -= sA0 * c0.y;
        acc0[jj].z -= sA0 * c0.z; acc0[jj].w -= sA0 * c0.w;
        acc1[jj].x -= sA1 * c1.x; acc1[jj].y -= sA1 * c1.y;
        acc1[jj].z -= sA1 * c1.z; acc1[jj].w -= sA1 * c1.w;
        *(float4*)(part_acc + base + (2 * kq) * DD + off[jj])     = acc0[jj];
        *(float4*)(part_acc + base + (2 * kq + 1) * DD + off[jj]) = acc1[jj];
    }
}

// ---------------------------------------------------------------------------
// K2 v6 (= v5): streaming reduce of 128 partials per (b,k). 512 blocks x
// 512 threads; 8-deep independent load chains; 16x32 float4 LDS reduce;
// intra-norm + global factor (sqrt(K)=8 -> 0.125).
// ---------------------------------------------------------------------------
__global__ __launch_bounds__(512) void netvlad_k2(
    const float* __restrict__ part_acc, float* __restrict__ out)
{
    const int b  = blockIdx.x >> 6;
    const int k  = blockIdx.x & 63;
    const int t  = threadIdx.x;
    const int d4 = t & 31;               // float4 column 0..31
    const int ps = t >> 5;               // p-slice 0..15

    float4 acc = make_float4(0.f, 0.f, 0.f, 0.f);
    const float* base = part_acc + ((size_t)(b * PP) * KK + k) * DD + d4 * 4;
    #pragma unroll
    for (int j = 0; j < 8; ++j) {        // p = j*16 + ps
        const float4 v = *(const float4*)(base + (size_t)(j * 16 + ps) * KK * DD);
        acc.x += v.x; acc.y += v.y; acc.z += v.z; acc.w += v.w;
    }

    __shared__ __align__(16) float4 red[16][32];
    red[ps][d4] = acc;
    __syncthreads();

    if (t < 32) {
        float4 v = red[0][t];
        #pragma unroll
        for (int s = 1; s < 16; ++s) {
            v.x += red[s][t].x; v.y += red[s][t].y;
            v.z += red[s][t].z; v.w += red[s][t].w;
        }
        float ss = v.x*v.x + v.y*v.y + v.z*v.z + v.w*v.w;
        #pragma unroll
        for (int m = 1; m < 32; m <<= 1) ss += __shfl_xor(ss, m);
        const float rn = 0.125f / fmaxf(sqrtf(ss), 1e-12f);
        v.x *= rn; v.y *= rn; v.z *= rn; v.w *= rn;
        *(float4*)(out + ((size_t)b * KK + k) * DD + t * 4) = v;
    }
}

extern "C" void kernel_launch(void* const* d_in, const int* in_sizes, int n_in,
                              void* d_out, int out_size, void* d_ws, size_t ws_size,
                              hipStream_t stream) {
    const float* x    = (const float*)d_in[0];   // [8, 2048, 128] fp32
    const float* cent = (const float*)d_in[1];   // [64, 128] fp32
    float* out = (float*)d_out;                  // [8, 8192] fp32

    float* part_acc = (float*)d_ws;              // 8*128*64*128 fp32 = 32 MB

    netvlad_k1<<<dim3(BB * PP), dim3(256), 0, stream>>>(x, cent, part_acc);
    netvlad_k2<<<dim3(BB * KK), dim3(512), 0, stream>>>(part_acc, out);
}

// Round 7
// 96.636 us; speedup vs baseline: 1.1696x; 1.1696x over previous
//
#include <hip/hip_runtime.h>
#include <math.h>

// NetVLAD: B=8, N=2048, D=128, K=64, fp32 in/out.
#define BB 8
#define NN 2048
#define DD 128
#define KK 64
#define PP 128           // blocks per batch for K1 (1024 blocks = 4/CU)
#define NPB (NN / PP)    // 16 descriptors per block, one pass

// ---------------------------------------------------------------------------
// K1 v7: v3's proven body (e0/e1 in REGISTERS — the 29 µs config) + the
// verified -sumA*c epilogue fold, with the register allocation PINNED.
//
// Series evidence: v3 (~29 µs) ran with a ~128-VGPR-class allocation and
// 16 waves/CU; v5/v6 (48-49 µs) were the same structure but the allocator
// flipped to a 64-VGPR target (v5: e-arrays spilled, +90 MB scratch traffic;
// v6: no spill but no spare regs to pipeline Phase B's 16 dot+shfl chains).
// amdgpu_waves_per_eu(4,4) pins exactly 4 waves/SIMD so the allocator can
// (and should) use ~96-128 VGPRs with zero spill and full chain interleave.
// cent is re-loaded in the epilogue (L2-hot) so cA/cB die after Phase B,
// keeping peak liveness below v3's own peak.
// ---------------------------------------------------------------------------
__global__ __launch_bounds__(256)
__attribute__((amdgpu_waves_per_eu(4, 4)))
void netvlad_k1(
    const float* __restrict__ x, const float* __restrict__ cent,
    float* __restrict__ part_acc)
{
    const int b    = blockIdx.x >> 7;    // / PP
    const int p    = blockIdx.x & 127;   // % PP
    const int t    = threadIdx.x;
    const int kq   = t >> 3;             // 0..31: owns k = {2kq, 2kq+1}
    const int pr   = t & 7;              // 0..7: owns d-range [pr*16, +16)
    const int dbase = pr * 16;
    const int wave = t >> 6;

    __shared__ __align__(16) float xs[NPB][DD];  // 8 KB: normalized descriptors
    __shared__ __align__(16) float sL[NPB][4];   // per-wave exp-sum partials

    // Rotated chunk offsets: slot jj -> chunk ((jj+pr)&3) of the 16-float
    // range (2-way bank alias max, free on gfx950).
    int off[4];
    #pragma unroll
    for (int jj = 0; jj < 4; ++jj) off[jj] = dbase + (((jj + pr) & 3) << 2);

    // ---- issue x loads first: row i0 = t>>4, floats [tl*4,+4) & [64+tl*4,+4)
    const int i0 = t >> 4, tl = t & 15;
    const float* xr = x + ((size_t)b * NN + (size_t)p * NPB + i0) * DD;
    float4 v0 = *(const float4*)(xr + tl * 4);
    float4 v1 = *(const float4*)(xr + 64 + tl * 4);

    // ---- centroid fragments + ||c_k||^2 (independent chain, overlaps loads)
    float4 cA[4], cB[4];
    float cn2a = 0.f, cn2b = 0.f;
    #pragma unroll
    for (int jj = 0; jj < 4; ++jj) {
        cA[jj] = *(const float4*)(cent + (2 * kq) * DD + off[jj]);
        cB[jj] = *(const float4*)(cent + (2 * kq + 1) * DD + off[jj]);
        cn2a += cA[jj].x*cA[jj].x + cA[jj].y*cA[jj].y + cA[jj].z*cA[jj].z + cA[jj].w*cA[jj].w;
        cn2b += cB[jj].x*cB[jj].x + cB[jj].y*cB[jj].y + cB[jj].z*cB[jj].z + cB[jj].w*cB[jj].w;
    }
    #pragma unroll
    for (int m = 1; m < 8; m <<= 1) {
        cn2a += __shfl_xor(cn2a, m);
        cn2b += __shfl_xor(cn2b, m);
    }

    // ---- normalize row i0 in registers, write xs once
    {
        float ss = v0.x*v0.x + v0.y*v0.y + v0.z*v0.z + v0.w*v0.w
                 + v1.x*v1.x + v1.y*v1.y + v1.z*v1.z + v1.w*v1.w;
        #pragma unroll
        for (int m = 1; m < 16; m <<= 1) ss += __shfl_xor(ss, m);
        const float rn = 1.0f / fmaxf(sqrtf(ss), 1e-12f);
        v0.x *= rn; v0.y *= rn; v0.z *= rn; v0.w *= rn;
        v1.x *= rn; v1.y *= rn; v1.z *= rn; v1.w *= rn;
        *(float4*)(&xs[i0][tl * 4])      = v0;
        *(float4*)(&xs[i0][64 + tl * 4]) = v1;
    }
    __syncthreads();   // bar 1: normalized tile visible

    // ---- Phase B: dots + exp, e values kept in REGISTERS (v3 config).
    // assign ∝ exp(||c||^2 - 2 xn·c)
    float e0[NPB], e1[NPB];
    #pragma unroll
    for (int i = 0; i < NPB; ++i) {
        float S0 = 0.f, S1 = 0.f;
        #pragma unroll
        for (int jj = 0; jj < 4; ++jj) {
            float4 v = *(const float4*)(&xs[i][off[jj]]);
            S0 += v.x*cA[jj].x + v.y*cA[jj].y + v.z*cA[jj].z + v.w*cA[jj].w;
            S1 += v.x*cB[jj].x + v.y*cB[jj].y + v.z*cB[jj].z + v.w*cB[jj].w;
        }
        #pragma unroll
        for (int m = 1; m < 8; m <<= 1) {   // reduce across the 8 d-parts
            S0 += __shfl_xor(S0, m);
            S1 += __shfl_xor(S1, m);
        }
        e0[i] = __expf(cn2a - 2.f * S0);
        e1[i] = __expf(cn2b - 2.f * S1);
        // per-wave softmax partial: sum this wave's 16 k's
        float es = e0[i] + e1[i];
        #pragma unroll
        for (int m = 8; m < 64; m <<= 1) es += __shfl_xor(es, m);
        if ((t & 63) == 0) sL[i][wave] = es;
    }
    __syncthreads();   // bar 2: sL complete

    // ---- Phase C: accumulate assign * xn (cA/cB dead here)
    float4 acc0[4], acc1[4];
    #pragma unroll
    for (int jj = 0; jj < 4; ++jj) {
        acc0[jj] = make_float4(0.f, 0.f, 0.f, 0.f);
        acc1[jj] = make_float4(0.f, 0.f, 0.f, 0.f);
    }
    float sA0 = 0.f, sA1 = 0.f;
    #pragma unroll
    for (int i = 0; i < NPB; ++i) {
        const float4 s4 = *(const float4*)(&sL[i][0]);   // broadcast
        const float rs = 1.0f / (s4.x + s4.y + s4.z + s4.w);
        const float a0 = e0[i] * rs, a1 = e1[i] * rs;
        sA0 += a0; sA1 += a1;
        #pragma unroll
        for (int jj = 0; jj < 4; ++jj) {
            float4 v = *(const float4*)(&xs[i][off[jj]]);
            acc0[jj].x += a0*v.x; acc0[jj].y += a0*v.y; acc0[jj].z += a0*v.z; acc0[jj].w += a0*v.w;
            acc1[jj].x += a1*v.x; acc1[jj].y += a1*v.y; acc1[jj].z += a1*v.z; acc1[jj].w += a1*v.w;
        }
    }

    // ---- epilogue: re-load centroid frags (L2-hot), fold -sumA*c (verified
    // in round 4), write partials.
    const size_t base = (size_t)(b * PP + p) * KK * DD;
    #pragma unroll
    for (int jj = 0; jj < 4; ++jj) {
        const float4 c0 = *(const float4*)(cent + (2 * kq) * DD + off[jj]);
        const float4 c1 = *(const float4*)(cent + (2 * kq + 1) * DD + off[jj]);
        acc0[jj].x -= sA0 * c0.x; acc0[jj].y -= sA0 * c0.y;
        acc0[jj].z -= sA0 * c0.z; acc0[jj].w -= sA0 * c0.w;
        acc1[jj].x -= sA1 * c1.x; acc1[jj].y -= sA1 * c1.y;
        acc1[jj].z -= sA1 * c1.z; acc1[jj].w -= sA1 * c1.w;
        *(float4*)(part_acc + base + (2 * kq) * DD + off[jj])     = acc0[jj];
        *(float4*)(part_acc + base + (2 * kq + 1) * DD + off[jj]) = acc1[jj];
    }
}

// ---------------------------------------------------------------------------
// K2 (= v5): streaming reduce of 128 partials per (b,k). 512 blocks x 512
// threads; 8-deep independent load chains; 16x32 float4 LDS reduce;
// intra-norm + global factor (sqrt(K)=8 -> 0.125).
// ---------------------------------------------------------------------------
__global__ __launch_bounds__(512) void netvlad_k2(
    const float* __restrict__ part_acc, float* __restrict__ out)
{
    const int b  = blockIdx.x >> 6;
    const int k  = blockIdx.x & 63;
    const int t  = threadIdx.x;
    const int d4 = t & 31;               // float4 column 0..31
    const int ps = t >> 5;               // p-slice 0..15

    float4 acc = make_float4(0.f, 0.f, 0.f, 0.f);
    const float* base = part_acc + ((size_t)(b * PP) * KK + k) * DD + d4 * 4;
    #pragma unroll
    for (int j = 0; j < 8; ++j) {        // p = j*16 + ps
        const float4 v = *(const float4*)(base + (size_t)(j * 16 + ps) * KK * DD);
        acc.x += v.x; acc.y += v.y; acc.z += v.z; acc.w += v.w;
    }

    __shared__ __align__(16) float4 red[16][32];
    red[ps][d4] = acc;
    __syncthreads();

    if (t < 32) {
        float4 v = red[0][t];
        #pragma unroll
        for (int s = 1; s < 16; ++s) {
            v.x += red[s][t].x; v.y += red[s][t].y;
            v.z += red[s][t].z; v.w += red[s][t].w;
        }
        float ss = v.x*v.x + v.y*v.y + v.z*v.z + v.w*v.w;
        #pragma unroll
        for (int m = 1; m < 32; m <<= 1) ss += __shfl_xor(ss, m);
        const float rn = 0.125f / fmaxf(sqrtf(ss), 1e-12f);
        v.x *= rn; v.y *= rn; v.z *= rn; v.w *= rn;
        *(float4*)(out + ((size_t)b * KK + k) * DD + t * 4) = v;
    }
}

extern "C" void kernel_launch(void* const* d_in, const int* in_sizes, int n_in,
                              void* d_out, int out_size, void* d_ws, size_t ws_size,
                              hipStream_t stream) {
    const float* x    = (const float*)d_in[0];   // [8, 2048, 128] fp32
    const float* cent = (const float*)d_in[1];   // [64, 128] fp32
    float* out = (float*)d_out;                  // [8, 8192] fp32

    float* part_acc = (float*)d_ws;              // 8*128*64*128 fp32 = 32 MB

    netvlad_k1<<<dim3(BB * PP), dim3(256), 0, stream>>>(x, cent, part_acc);
    netvlad_k2<<<dim3(BB * KK), dim3(512), 0, stream>>>(part_acc, out);
}

// Round 8
// 92.822 us; speedup vs baseline: 1.2176x; 1.0411x over previous
//
#include <hip/hip_runtime.h>
#include <math.h>

// NetVLAD: B=8, N=2048, D=128, K=64, fp32 in/out.
#define BB 8
#define NN 2048
#define DD 128
#define KK 64
#define PP 64            // partial groups per batch (512 blocks = 2/CU)
#define NPB (NN / PP)    // 32 descriptors per block
#define TI 16            // descriptors per half

// ---------------------------------------------------------------------------
// K1 v8: 512-thread blocks = two independent 256-thread halves, each running
// v7's verified body on its own 16-descriptor tile; halves combine their
// accumulators in LDS so each block writes ONE partial (16 MB total instead
// of 32 MB) at UNCHANGED occupancy (2 blk/CU x 8 waves = 16 waves/CU, same
// as v7's 4 x 4). cA/cB stay live through the epilogue (peak ~110 VGPR,
// under the 128 cap pinned by waves_per_eu(4,4) -> no spill).
//   bar1: xs[h] tiles normalized/visible
//   bar2: sL[h] softmax partials
//   (Phase C in regs)
//   bar3: h0's acc + sumA staged in LDS -> h1 adds, folds -sumA*c, writes.
// ---------------------------------------------------------------------------
__global__ __launch_bounds__(512)
__attribute__((amdgpu_waves_per_eu(4, 4)))
void netvlad_k1(
    const float* __restrict__ x, const float* __restrict__ cent,
    float* __restrict__ part_acc)
{
    const int b    = blockIdx.x >> 6;    // / PP
    const int p    = blockIdx.x & 63;    // % PP
    const int t    = threadIdx.x;
    const int h    = t >> 8;             // half 0/1
    const int u    = t & 255;            // index within half
    const int kq   = u >> 3;             // 0..31: owns k = {2kq, 2kq+1}
    const int pr   = u & 7;              // 0..7: owns d-range [pr*16, +16)
    const int dbase = pr * 16;
    const int wv   = u >> 6;             // wave-in-half 0..3

    __shared__ __align__(16) float xs[2][TI][DD];   // 16 KB normalized tiles
    __shared__ __align__(16) float sL[2][TI][4];    // softmax wave-partials
    __shared__ __align__(16) float comb[256][36];   // 36 KB combine (36-stride: ~bank floor)
    __shared__ float sAc[32][2];                    // h0's sumA per kq

    // Rotated chunk offsets: slot jj -> chunk ((jj+pr)&3) (<=2-way alias).
    int off[4];
    #pragma unroll
    for (int jj = 0; jj < 4; ++jj) off[jj] = dbase + (((jj + pr) & 3) << 2);

    // ---- x loads: this half's tile, row i0 = u>>4. 16B/lane coalesced.
    const int i0 = u >> 4, tl = u & 15;
    const float* xr = x + ((size_t)b * NN + (size_t)p * NPB + h * TI + i0) * DD;
    float4 v0 = *(const float4*)(xr + tl * 4);
    float4 v1 = *(const float4*)(xr + 64 + tl * 4);

    // ---- centroid fragments + ||c_k||^2 (overlaps x loads; kept live)
    float4 cA[4], cB[4];
    float cn2a = 0.f, cn2b = 0.f;
    #pragma unroll
    for (int jj = 0; jj < 4; ++jj) {
        cA[jj] = *(const float4*)(cent + (2 * kq) * DD + off[jj]);
        cB[jj] = *(const float4*)(cent + (2 * kq + 1) * DD + off[jj]);
        cn2a += cA[jj].x*cA[jj].x + cA[jj].y*cA[jj].y + cA[jj].z*cA[jj].z + cA[jj].w*cA[jj].w;
        cn2b += cB[jj].x*cB[jj].x + cB[jj].y*cB[jj].y + cB[jj].z*cB[jj].z + cB[jj].w*cB[jj].w;
    }
    #pragma unroll
    for (int m = 1; m < 8; m <<= 1) {
        cn2a += __shfl_xor(cn2a, m);
        cn2b += __shfl_xor(cn2b, m);
    }

    // ---- normalize row i0 in registers (16-lane groups), write xs[h] once
    {
        float ss = v0.x*v0.x + v0.y*v0.y + v0.z*v0.z + v0.w*v0.w
                 + v1.x*v1.x + v1.y*v1.y + v1.z*v1.z + v1.w*v1.w;
        #pragma unroll
        for (int m = 1; m < 16; m <<= 1) ss += __shfl_xor(ss, m);
        const float rn = 1.0f / fmaxf(sqrtf(ss), 1e-12f);
        v0.x *= rn; v0.y *= rn; v0.z *= rn; v0.w *= rn;
        v1.x *= rn; v1.y *= rn; v1.z *= rn; v1.w *= rn;
        *(float4*)(&xs[h][i0][tl * 4])      = v0;
        *(float4*)(&xs[h][i0][64 + tl * 4]) = v1;
    }
    __syncthreads();   // bar 1

    // ---- Phase B: dots + exp (e in registers). assign ∝ exp(||c||^2 - 2 xn·c)
    float e0[TI], e1[TI];
    #pragma unroll
    for (int i = 0; i < TI; ++i) {
        float S0 = 0.f, S1 = 0.f;
        #pragma unroll
        for (int jj = 0; jj < 4; ++jj) {
            float4 v = *(const float4*)(&xs[h][i][off[jj]]);
            S0 += v.x*cA[jj].x + v.y*cA[jj].y + v.z*cA[jj].z + v.w*cA[jj].w;
            S1 += v.x*cB[jj].x + v.y*cB[jj].y + v.z*cB[jj].z + v.w*cB[jj].w;
        }
        #pragma unroll
        for (int m = 1; m < 8; m <<= 1) {   // reduce across the 8 d-parts
            S0 += __shfl_xor(S0, m);
            S1 += __shfl_xor(S1, m);
        }
        e0[i] = __expf(cn2a - 2.f * S0);
        e1[i] = __expf(cn2b - 2.f * S1);
        float es = e0[i] + e1[i];
        #pragma unroll
        for (int m = 8; m < 64; m <<= 1) es += __shfl_xor(es, m);
        if ((u & 63) == 0) sL[h][i][wv] = es;
    }
    __syncthreads();   // bar 2

    // ---- Phase C: accumulate assign * xn
    float4 acc0[4], acc1[4];
    #pragma unroll
    for (int jj = 0; jj < 4; ++jj) {
        acc0[jj] = make_float4(0.f, 0.f, 0.f, 0.f);
        acc1[jj] = make_float4(0.f, 0.f, 0.f, 0.f);
    }
    float sA0 = 0.f, sA1 = 0.f;
    #pragma unroll
    for (int i = 0; i < TI; ++i) {
        const float4 s4 = *(const float4*)(&sL[h][i][0]);   // broadcast
        const float rs = 1.0f / (s4.x + s4.y + s4.z + s4.w);
        const float a0 = e0[i] * rs, a1 = e1[i] * rs;
        sA0 += a0; sA1 += a1;
        #pragma unroll
        for (int jj = 0; jj < 4; ++jj) {
            float4 v = *(const float4*)(&xs[h][i][off[jj]]);
            acc0[jj].x += a0*v.x; acc0[jj].y += a0*v.y; acc0[jj].z += a0*v.z; acc0[jj].w += a0*v.w;
            acc1[jj].x += a1*v.x; acc1[jj].y += a1*v.y; acc1[jj].z += a1*v.z; acc1[jj].w += a1*v.w;
        }
    }

    // ---- combine halves: h0 stages, h1 adds + folds + writes
    if (h == 0) {
        #pragma unroll
        for (int jj = 0; jj < 4; ++jj) {
            *(float4*)(&comb[u][jj * 4])      = acc0[jj];
            *(float4*)(&comb[u][16 + jj * 4]) = acc1[jj];
        }
        if (pr == 0) { sAc[kq][0] = sA0; sAc[kq][1] = sA1; }
    }
    __syncthreads();   // bar 3: h0's accumulators visible

    if (h == 1) {
        sA0 += sAc[kq][0];
        sA1 += sAc[kq][1];
        const size_t base = (size_t)(b * PP + p) * KK * DD;
        #pragma unroll
        for (int jj = 0; jj < 4; ++jj) {
            const float4 o0 = *(const float4*)(&comb[u][jj * 4]);
            const float4 o1 = *(const float4*)(&comb[u][16 + jj * 4]);
            float4 r0 = acc0[jj], r1 = acc1[jj];
            r0.x += o0.x; r0.y += o0.y; r0.z += o0.z; r0.w += o0.w;
            r1.x += o1.x; r1.y += o1.y; r1.z += o1.z; r1.w += o1.w;
            r0.x -= sA0 * cA[jj].x; r0.y -= sA0 * cA[jj].y;
            r0.z -= sA0 * cA[jj].z; r0.w -= sA0 * cA[jj].w;
            r1.x -= sA1 * cB[jj].x; r1.y -= sA1 * cB[jj].y;
            r1.z -= sA1 * cB[jj].z; r1.w -= sA1 * cB[jj].w;
            *(float4*)(part_acc + base + (2 * kq) * DD + off[jj])     = r0;
            *(float4*)(part_acc + base + (2 * kq + 1) * DD + off[jj]) = r1;
        }
    }
}

// ---------------------------------------------------------------------------
// K2 v8: sum 64 partials per (b,k) (4-deep independent chains, 512 threads),
// intra-normalize, apply global factor (sqrt(K)=8 -> 0.125; -sumA*c already
// folded in K1). Grid: BB*KK = 512 blocks.
// ---------------------------------------------------------------------------
__global__ __launch_bounds__(512) void netvlad_k2(
    const float* __restrict__ part_acc, float* __restrict__ out)
{
    const int b  = blockIdx.x >> 6;
    const int k  = blockIdx.x & 63;
    const int t  = threadIdx.x;
    const int d4 = t & 31;               // float4 column 0..31
    const int ps = t >> 5;               // p-slice 0..15

    float4 acc = make_float4(0.f, 0.f, 0.f, 0.f);
    const float* base = part_acc + ((size_t)(b * PP) * KK + k) * DD + d4 * 4;
    #pragma unroll
    for (int j = 0; j < 4; ++j) {        // p = j*16 + ps
        const float4 v = *(const float4*)(base + (size_t)(j * 16 + ps) * KK * DD);
        acc.x += v.x; acc.y += v.y; acc.z += v.z; acc.w += v.w;
    }

    __shared__ __align__(16) float4 red[16][32];
    red[ps][d4] = acc;
    __syncthreads();

    if (t < 32) {
        float4 v = red[0][t];
        #pragma unroll
        for (int s = 1; s < 16; ++s) {
            v.x += red[s][t].x; v.y += red[s][t].y;
            v.z += red[s][t].z; v.w += red[s][t].w;
        }
        float ss = v.x*v.x + v.y*v.y + v.z*v.z + v.w*v.w;
        #pragma unroll
        for (int m = 1; m < 32; m <<= 1) ss += __shfl_xor(ss, m);
        const float rn = 0.125f / fmaxf(sqrtf(ss), 1e-12f);
        v.x *= rn; v.y *= rn; v.z *= rn; v.w *= rn;
        *(float4*)(out + ((size_t)b * KK + k) * DD + t * 4) = v;
    }
}

extern "C" void kernel_launch(void* const* d_in, const int* in_sizes, int n_in,
                              void* d_out, int out_size, void* d_ws, size_t ws_size,
                              hipStream_t stream) {
    const float* x    = (const float*)d_in[0];   // [8, 2048, 128] fp32
    const float* cent = (const float*)d_in[1];   // [64, 128] fp32
    float* out = (float*)d_out;                  // [8, 8192] fp32

    float* part_acc = (float*)d_ws;              // 8*64*64*128 fp32 = 16 MB

    netvlad_k1<<<dim3(BB * PP), dim3(512), 0, stream>>>(x, cent, part_acc);
    netvlad_k2<<<dim3(BB * KK), dim3(512), 0, stream>>>(part_acc, out);
}

// Round 9
// 87.123 us; speedup vs baseline: 1.2973x; 1.0654x over previous
//
#include <hip/hip_runtime.h>
#include <math.h>

// NetVLAD: B=8, N=2048, D=128, K=64, fp32 in/out.
#define BB 8
#define NN 2048
#define DD 128
#define KK 64
#define PP 64            // partial groups per batch (512 blocks = 2/CU)
#define NPB (NN / PP)    // 32 descriptors per block
#define TI 16            // descriptors per half

// ---------------------------------------------------------------------------
// K1 v9: v8 (two 256-thread halves, LDS combine, ONE 16 MB partial set)
// with the v7-proven register-liveness fix restored: cA/cB DIE after
// Phase B; the h==1 epilogue re-loads centroid fragments from cent
// (L2-hot, 2 MB total) for the -sumA*c fold. Peak liveness in Phase C
// drops ~115 -> ~80 VGPRs, safely under the 128 cap pinned by
// waves_per_eu(4,4) -> no scratch traffic (v5 lesson: spills cost ~20 µs).
//   bar1: xs[h] tiles normalized/visible
//   bar2: sL[h] softmax partials
//   (Phase C in regs)
//   bar3: h0's acc + sumA staged in LDS -> h1 adds, folds, writes.
// ---------------------------------------------------------------------------
__global__ __launch_bounds__(512)
__attribute__((amdgpu_waves_per_eu(4, 4)))
void netvlad_k1(
    const float* __restrict__ x, const float* __restrict__ cent,
    float* __restrict__ part_acc)
{
    const int b    = blockIdx.x >> 6;    // / PP
    const int p    = blockIdx.x & 63;    // % PP
    const int t    = threadIdx.x;
    const int h    = t >> 8;             // half 0/1
    const int u    = t & 255;            // index within half
    const int kq   = u >> 3;             // 0..31: owns k = {2kq, 2kq+1}
    const int pr   = u & 7;              // 0..7: owns d-range [pr*16, +16)
    const int dbase = pr * 16;
    const int wv   = u >> 6;             // wave-in-half 0..3

    __shared__ __align__(16) float xs[2][TI][DD];   // 16 KB normalized tiles
    __shared__ __align__(16) float sL[2][TI][4];    // softmax wave-partials
    __shared__ __align__(16) float comb[256][36];   // 36 KB combine
    __shared__ float sAc[32][2];                    // h0's sumA per kq

    // Rotated chunk offsets: slot jj -> chunk ((jj+pr)&3) (<=2-way alias).
    int off[4];
    #pragma unroll
    for (int jj = 0; jj < 4; ++jj) off[jj] = dbase + (((jj + pr) & 3) << 2);

    // ---- x loads: this half's tile, row i0 = u>>4. 16B/lane coalesced.
    const int i0 = u >> 4, tl = u & 15;
    const float* xr = x + ((size_t)b * NN + (size_t)p * NPB + h * TI + i0) * DD;
    float4 v0 = *(const float4*)(xr + tl * 4);
    float4 v1 = *(const float4*)(xr + 64 + tl * 4);

    // ---- centroid fragments + ||c_k||^2 (overlaps x loads; die after B)
    float4 cA[4], cB[4];
    float cn2a = 0.f, cn2b = 0.f;
    #pragma unroll
    for (int jj = 0; jj < 4; ++jj) {
        cA[jj] = *(const float4*)(cent + (2 * kq) * DD + off[jj]);
        cB[jj] = *(const float4*)(cent + (2 * kq + 1) * DD + off[jj]);
        cn2a += cA[jj].x*cA[jj].x + cA[jj].y*cA[jj].y + cA[jj].z*cA[jj].z + cA[jj].w*cA[jj].w;
        cn2b += cB[jj].x*cB[jj].x + cB[jj].y*cB[jj].y + cB[jj].z*cB[jj].z + cB[jj].w*cB[jj].w;
    }
    #pragma unroll
    for (int m = 1; m < 8; m <<= 1) {
        cn2a += __shfl_xor(cn2a, m);
        cn2b += __shfl_xor(cn2b, m);
    }

    // ---- normalize row i0 in registers (16-lane groups), write xs[h] once
    {
        float ss = v0.x*v0.x + v0.y*v0.y + v0.z*v0.z + v0.w*v0.w
                 + v1.x*v1.x + v1.y*v1.y + v1.z*v1.z + v1.w*v1.w;
        #pragma unroll
        for (int m = 1; m < 16; m <<= 1) ss += __shfl_xor(ss, m);
        const float rn = 1.0f / fmaxf(sqrtf(ss), 1e-12f);
        v0.x *= rn; v0.y *= rn; v0.z *= rn; v0.w *= rn;
        v1.x *= rn; v1.y *= rn; v1.z *= rn; v1.w *= rn;
        *(float4*)(&xs[h][i0][tl * 4])      = v0;
        *(float4*)(&xs[h][i0][64 + tl * 4]) = v1;
    }
    __syncthreads();   // bar 1

    // ---- Phase B: dots + exp (e in registers). assign ∝ exp(||c||^2 - 2 xn·c)
    float e0[TI], e1[TI];
    #pragma unroll
    for (int i = 0; i < TI; ++i) {
        float S0 = 0.f, S1 = 0.f;
        #pragma unroll
        for (int jj = 0; jj < 4; ++jj) {
            float4 v = *(const float4*)(&xs[h][i][off[jj]]);
            S0 += v.x*cA[jj].x + v.y*cA[jj].y + v.z*cA[jj].z + v.w*cA[jj].w;
            S1 += v.x*cB[jj].x + v.y*cB[jj].y + v.z*cB[jj].z + v.w*cB[jj].w;
        }
        #pragma unroll
        for (int m = 1; m < 8; m <<= 1) {   // reduce across the 8 d-parts
            S0 += __shfl_xor(S0, m);
            S1 += __shfl_xor(S1, m);
        }
        e0[i] = __expf(cn2a - 2.f * S0);
        e1[i] = __expf(cn2b - 2.f * S1);
        float es = e0[i] + e1[i];
        #pragma unroll
        for (int m = 8; m < 64; m <<= 1) es += __shfl_xor(es, m);
        if ((u & 63) == 0) sL[h][i][wv] = es;
    }
    __syncthreads();   // bar 2 (cA/cB dead from here)

    // ---- Phase C: accumulate assign * xn
    float4 acc0[4], acc1[4];
    #pragma unroll
    for (int jj = 0; jj < 4; ++jj) {
        acc0[jj] = make_float4(0.f, 0.f, 0.f, 0.f);
        acc1[jj] = make_float4(0.f, 0.f, 0.f, 0.f);
    }
    float sA0 = 0.f, sA1 = 0.f;
    #pragma unroll
    for (int i = 0; i < TI; ++i) {
        const float4 s4 = *(const float4*)(&sL[h][i][0]);   // broadcast
        const float rs = 1.0f / (s4.x + s4.y + s4.z + s4.w);
        const float a0 = e0[i] * rs, a1 = e1[i] * rs;
        sA0 += a0; sA1 += a1;
        #pragma unroll
        for (int jj = 0; jj < 4; ++jj) {
            float4 v = *(const float4*)(&xs[h][i][off[jj]]);
            acc0[jj].x += a0*v.x; acc0[jj].y += a0*v.y; acc0[jj].z += a0*v.z; acc0[jj].w += a0*v.w;
            acc1[jj].x += a1*v.x; acc1[jj].y += a1*v.y; acc1[jj].z += a1*v.z; acc1[jj].w += a1*v.w;
        }
    }

    // ---- combine halves: h0 stages, h1 adds + folds (cent re-loaded,
    // L2-hot) + writes. v7-proven liveness pattern.
    if (h == 0) {
        #pragma unroll
        for (int jj = 0; jj < 4; ++jj) {
            *(float4*)(&comb[u][jj * 4])      = acc0[jj];
            *(float4*)(&comb[u][16 + jj * 4]) = acc1[jj];
        }
        if (pr == 0) { sAc[kq][0] = sA0; sAc[kq][1] = sA1; }
    }
    __syncthreads();   // bar 3: h0's accumulators visible

    if (h == 1) {
        sA0 += sAc[kq][0];
        sA1 += sAc[kq][1];
        const size_t base = (size_t)(b * PP + p) * KK * DD;
        #pragma unroll
        for (int jj = 0; jj < 4; ++jj) {
            const float4 c0 = *(const float4*)(cent + (2 * kq) * DD + off[jj]);
            const float4 c1 = *(const float4*)(cent + (2 * kq + 1) * DD + off[jj]);
            const float4 o0 = *(const float4*)(&comb[u][jj * 4]);
            const float4 o1 = *(const float4*)(&comb[u][16 + jj * 4]);
            float4 r0 = acc0[jj], r1 = acc1[jj];
            r0.x += o0.x; r0.y += o0.y; r0.z += o0.z; r0.w += o0.w;
            r1.x += o1.x; r1.y += o1.y; r1.z += o1.z; r1.w += o1.w;
            r0.x -= sA0 * c0.x; r0.y -= sA0 * c0.y;
            r0.z -= sA0 * c0.z; r0.w -= sA0 * c0.w;
            r1.x -= sA1 * c1.x; r1.y -= sA1 * c1.y;
            r1.z -= sA1 * c1.z; r1.w -= sA1 * c1.w;
            *(float4*)(part_acc + base + (2 * kq) * DD + off[jj])     = r0;
            *(float4*)(part_acc + base + (2 * kq + 1) * DD + off[jj]) = r1;
        }
    }
}

// ---------------------------------------------------------------------------
// K2 v9 (= v8): sum 64 partials per (b,k) (4-deep independent chains, 512
// threads), intra-normalize, apply global factor (sqrt(K)=8 -> 0.125;
// -sumA*c already folded in K1). Grid: BB*KK = 512 blocks.
// ---------------------------------------------------------------------------
__global__ __launch_bounds__(512) void netvlad_k2(
    const float* __restrict__ part_acc, float* __restrict__ out)
{
    const int b  = blockIdx.x >> 6;
    const int k  = blockIdx.x & 63;
    const int t  = threadIdx.x;
    const int d4 = t & 31;               // float4 column 0..31
    const int ps = t >> 5;               // p-slice 0..15

    float4 acc = make_float4(0.f, 0.f, 0.f, 0.f);
    const float* base = part_acc + ((size_t)(b * PP) * KK + k) * DD + d4 * 4;
    #pragma unroll
    for (int j = 0; j < 4; ++j) {        // p = j*16 + ps
        const float4 v = *(const float4*)(base + (size_t)(j * 16 + ps) * KK * DD);
        acc.x += v.x; acc.y += v.y; acc.z += v.z; acc.w += v.w;
    }

    __shared__ __align__(16) float4 red[16][32];
    red[ps][d4] = acc;
    __syncthreads();

    if (t < 32) {
        float4 v = red[0][t];
        #pragma unroll
        for (int s = 1; s < 16; ++s) {
            v.x += red[s][t].x; v.y += red[s][t].y;
            v.z += red[s][t].z; v.w += red[s][t].w;
        }
        float ss = v.x*v.x + v.y*v.y + v.z*v.z + v.w*v.w;
        #pragma unroll
        for (int m = 1; m < 32; m <<= 1) ss += __shfl_xor(ss, m);
        const float rn = 0.125f / fmaxf(sqrtf(ss), 1e-12f);
        v.x *= rn; v.y *= rn; v.z *= rn; v.w *= rn;
        *(float4*)(out + ((size_t)b * KK + k) * DD + t * 4) = v;
    }
}

extern "C" void kernel_launch(void* const* d_in, const int* in_sizes, int n_in,
                              void* d_out, int out_size, void* d_ws, size_t ws_size,
                              hipStream_t stream) {
    const float* x    = (const float*)d_in[0];   // [8, 2048, 128] fp32
    const float* cent = (const float*)d_in[1];   // [64, 128] fp32
    float* out = (float*)d_out;                  // [8, 8192] fp32

    float* part_acc = (float*)d_ws;              // 8*64*64*128 fp32 = 16 MB

    netvlad_k1<<<dim3(BB * PP), dim3(512), 0, stream>>>(x, cent, part_acc);
    netvlad_k2<<<dim3(BB * KK), dim3(512), 0, stream>>>(part_acc, out);
}